// Round 8
// baseline (71.953 us; speedup 1.0000x reference)
//
#include <hip/hip_runtime.h>

// Problem constants (fixed shapes from setup_inputs)
constexpr int NB = 8;     // batch
constexpr int ND = 1024;  // d = 32*32 cells
constexpr int NS = 500;   // noise samples n
constexpr int NK = 16;    // k
constexpr int NC = 3;     // channels
constexpr int NH = 1024;  // H
constexpr int NW = 1024;  // W
constexpr int NP = 64;    // patch size
constexpr int PTOP = 16;  // (p - sh)/2
constexpr int PLEFT = 16; // (p - sw)/2
constexpr float SIGMA = 0.05f;

// ---- Phase 1: normalize (blocks 0-7) + zero counts (all 64 blocks) ----
__global__ void normalize_kernel(const float* __restrict__ scores,
                                 float* __restrict__ s_norm,
                                 int* __restrict__ counts) {
    int blk = blockIdx.x;   // 64 blocks
    int t = threadIdx.x;

    // zero counts: 8*16*1024 ints = 32768 int4; 512 int4 per block
    int4 z4 = make_int4(0, 0, 0, 0);
    ((int4*)counts)[blk * 512 + t] = z4;
    ((int4*)counts)[blk * 512 + 256 + t] = z4;

    if (blk >= NB) return;
    int b = blk;
    float v[4];
#pragma unroll
    for (int q = 0; q < 4; q++) v[q] = scores[b * ND + t + 256 * q];
    float mn = fminf(fminf(v[0], v[1]), fminf(v[2], v[3]));
    float mx = fmaxf(fmaxf(v[0], v[1]), fmaxf(v[2], v[3]));
#pragma unroll
    for (int off = 1; off < 64; off <<= 1) {
        mn = fminf(mn, __shfl_xor(mn, off));
        mx = fmaxf(mx, __shfl_xor(mx, off));
    }
    __shared__ float smn[4], smx[4];
    int wave = t >> 6, lane = t & 63;
    if (lane == 0) { smn[wave] = mn; smx[wave] = mx; }
    __syncthreads();
    mn = fminf(fminf(smn[0], smn[1]), fminf(smn[2], smn[3]));
    mx = fmaxf(fmaxf(smx[0], smx[1]), fmaxf(smx[2], smx[3]));
    float den = mx - mn + 1e-5f;
#pragma unroll
    for (int q = 0; q < 4; q++)
        s_norm[b * ND + t + 256 * q] = (v[q] - mn) / den;
}

// ---------------- Phase 2: wave-per-sample top-16 -> integer histogram ----------------
__global__ void topk_kernel(const float* __restrict__ s_norm,
                            const float* __restrict__ noise,
                            int* __restrict__ counts) {
    int t = threadIdx.x;
    int wave = t >> 6, lane = t & 63;
    int sid = blockIdx.x * 4 + wave;          // 0 .. NB*NS-1 (grid is exact)
    int b = sid / NS;

    const float* sp = s_norm + b * ND;
    const float* npp = noise + (size_t)sid * ND;

    float v[16];
#pragma unroll
    for (int q = 0; q < 16; q++) {
        int j = q * 64 + lane;
        v[q] = sp[j] + npp[j] * SIGMA;
    }

    int myj = 0x7fffffff;
    for (int it = 0; it < NK; it++) {
        float bv = v[0];
        int bq = 0;
#pragma unroll
        for (int q = 1; q < 16; q++)
            if (v[q] > bv) { bv = v[q]; bq = q; }
        int bj = bq * 64 + lane;
#pragma unroll
        for (int off = 1; off < 64; off <<= 1) {
            float ov = __shfl_xor(bv, off);
            int oj = __shfl_xor(bj, off);
            if (ov > bv || (ov == bv && oj < bj)) { bv = ov; bj = oj; }
        }
        if (lane == it) myj = bj;
        int wq = bj >> 6, wl = bj & 63;
#pragma unroll
        for (int q = 0; q < 16; q++)
            v[q] = (q == wq && lane == wl) ? -1e30f : v[q];
    }

    int rank = 0;
#pragma unroll
    for (int u = 0; u < NK; u++) {
        int other = __shfl(myj, u);
        rank += (other < myj) ? 1 : 0;
    }
    if (lane < NK)
        atomicAdd(&counts[(b * NK + rank) * ND + myj], 1);
}

// ---------------- Phase 2.5: per-batch union of nonzero cells ----------------
// Block per b. Entry = packed (i<<15)|(j<<5)|edge_flags; + 16 f32 weights.
__global__ void union_kernel(const int* __restrict__ counts,
                             int* __restrict__ ucell,
                             float* __restrict__ uw,
                             int* __restrict__ nunion) {
    int b = blockIdx.x;
    int t = threadIdx.x;
    int lane = t & 63, wave = t >> 6;
    const int* cp = counts + b * NK * ND;

    unsigned nz = 0;
    for (int kk = 0; kk < NK; kk++) {
        int4 c4 = *(const int4*)(cp + kk * ND + t * 4);
        if (c4.x) nz |= 1;
        if (c4.y) nz |= 2;
        if (c4.z) nz |= 4;
        if (c4.w) nz |= 8;
    }
    int cnt = __popc(nz);
    int incl = cnt;
#pragma unroll
    for (int off = 1; off < 64; off <<= 1) {
        int o = __shfl_up(incl, off);
        if (lane >= off) incl += o;
    }
    int excl = incl - cnt;
    __shared__ int wtot[4];
    if (lane == 63) wtot[wave] = incl;
    __syncthreads();
    int base = 0;
    for (int w = 0; w < wave; w++) base += wtot[w];
    int pos = base + excl;

    const float invn = 1.0f / (float)NS;
    int* up = ucell + b * ND;
    float* wp = uw + (size_t)b * ND * NK;
#pragma unroll
    for (int q = 0; q < 4; q++) {
        if (nz & (1u << q)) {
            int cell = t * 4 + q;
            int i = cell >> 5, j = cell & 31;
            int ent = (i << 15) | (j << 5) |
                      ((i == 0) ? 1 : 0) | ((i == 31) ? 2 : 0) |
                      ((j == 0) ? 4 : 0) | ((j == 31) ? 8 : 0);
            up[pos] = ent;
            for (int kk = 0; kk < NK; kk++)
                wp[(size_t)pos * NK + kk] = (float)cp[kk * ND + cell] * invn;
            pos++;
        }
    }
    if (t == 0) nunion[b] = wtot[0] + wtot[1] + wtot[2] + wtot[3];
}

// ---------------- Phase 3: union gather, one output row per block ----------------
// Grid: blk = ii*24 + bc (bc = b*3+c; blk%8==bc%8 pins each image's blocks to
// one XCD). ii = kq*64 + y: block computes output row y for 8 kk (half kq).
// Wave w (0..3) handles entries e = w (mod 4): entry word + weights are
// WAVE-UNIFORM addresses (scalar/broadcast loads, no LDS staging, no barriers
// in the main loop). 4-deep batched x-loads hide latency; tiny LDS (7 KB) only
// for the final 4-way cross-wave reduce -> ~8 blocks/CU occupancy (vs 3 before).
// Every output element written exactly once (wave 0).
__global__ void __launch_bounds__(256, 8)
gather_kernel(const int* __restrict__ ucell,
              const float* __restrict__ uw,
              const int* __restrict__ nunion,
              const float* __restrict__ x_high,
              float* __restrict__ out) {
    int blk = blockIdx.x;
    int bc = blk % 24;
    int ii = blk / 24;           // 0..127
    int y  = ii & 63;
    int kq = ii >> 6;            // kk half: 0 or 1
    int b = bc / 3, c = bc % 3;
    int t = threadIdx.x;
    int w = t >> 6;              // wave = entry slot (0..3)
    int x = t & 63;

    int U = nunion[b];
    const int* up = ucell + b * ND;
    const float* wp = uw + (size_t)b * ND * NK + kq * 8;
    const float* xp = x_high + (size_t)bc * (NH * NW);

    int ym = y - PTOP;           // [-16, 48), uniform per block
    int xm = x - PLEFT;          // [-16, 48), per lane
    int off = ym * NW + xm;
    int mask = ((ym < 0) ? 1 : 0) | ((ym >= 32) ? 2 : 0) |
               ((xm < 0) ? 4 : 0) | ((xm >= 32) ? 8 : 0);

    float acc[8];
#pragma unroll
    for (int q = 0; q < 8; q++) acc[q] = 0.f;

    // entries e = w, w+4, w+8, ... ; 4 per chunk, loads batched before use
    for (int e0 = w; e0 < U; e0 += 16) {
        float vv[4];
        int es[4];
        // phase A: 4 independent x-loads
#pragma unroll
        for (int j = 0; j < 4; j++) {
            int e = e0 + 4 * j;
            bool in = (e < U);
            int ee = in ? e : 0;
            es[j] = ee;
            int ent = up[ee];                    // wave-uniform
            bool ok = in && ((ent & mask) == 0);
            int idx = ok ? ((ent & ~15) + off) : 0;
            float v = xp[idx];
            vv[j] = ok ? v : 0.f;
        }
        // phase B: consume (weights wave-uniform)
#pragma unroll
        for (int j = 0; j < 4; j++) {
            const float4* wq = (const float4*)(wp + (size_t)es[j] * NK);
            float4 w0 = wq[0], w1 = wq[1];
            float v = vv[j];
            acc[0] += w0.x * v; acc[1] += w0.y * v;
            acc[2] += w0.z * v; acc[3] += w0.w * v;
            acc[4] += w1.x * v; acc[5] += w1.y * v;
            acc[6] += w1.z * v; acc[7] += w1.w * v;
        }
    }

    // cross-wave reduce: waves 1-3 park partials in LDS (pad 9 -> conflict-free),
    // wave 0 sums and stores (each output written exactly once).
    __shared__ float red[3][64][9];
    if (w > 0) {
#pragma unroll
        for (int q = 0; q < 8; q++) red[w - 1][x][q] = acc[q];
    }
    __syncthreads();
    if (w == 0) {
#pragma unroll
        for (int q = 0; q < 8; q++) {
            float s = acc[q] + red[0][x][q] + red[1][x][q] + red[2][x][q];
            int kk = kq * 8 + q;
            out[((size_t)(b * NK + kk) * NC + c) * (NP * NP) + y * NP + x] = s;
        }
    }
}

extern "C" void kernel_launch(void* const* d_in, const int* in_sizes, int n_in,
                              void* d_out, int out_size, void* d_ws, size_t ws_size,
                              hipStream_t stream) {
    const float* scores = (const float*)d_in[0];
    const float* x_high = (const float*)d_in[1];
    const float* noise  = (const float*)d_in[2];

    char* ws = (char*)d_ws;
    float* s_norm = (float*)ws;                            // 32 KB
    int* counts   = (int*)(ws + 32 * 1024);                // 512 KB (int4-aligned)
    int* ucell    = (int*)(ws + 544 * 1024);               // 32 KB
    float* uw     = (float*)(ws + 576 * 1024);             // 512 KB
    int* nunion   = (int*)(ws + 1088 * 1024);              // 32 B

    normalize_kernel<<<64, 256, 0, stream>>>(scores, s_norm, counts);
    topk_kernel<<<NB * NS / 4, 256, 0, stream>>>(s_norm, noise, counts);
    union_kernel<<<NB, 256, 0, stream>>>(counts, ucell, uw, nunion);
    gather_kernel<<<24 * 128, 256, 0, stream>>>(ucell, uw, nunion, x_high,
                                                (float*)d_out);
}